// Round 1
// baseline (3176.517 us; speedup 1.0000x reference)
//
#include <hip/hip_runtime.h>
#include <hip/hip_bf16.h>

#define DIM 384
#define NHEADS 12
#define NTOK 49
#define NWIN 4096
#define MTOT (NWIN * NTOK)   /* 200704 */
#define QKVN (3 * DIM)       /* 1152 */
#define QSCALE 0.17677669529663687f

using f32x4  = __attribute__((ext_vector_type(4))) float;
using bf16x8 = __attribute__((ext_vector_type(8))) short;

__device__ __forceinline__ unsigned short f2bf(float f) {
  __hip_bfloat16 h = __float2bfloat16(f);
  return __builtin_bit_cast(unsigned short, h);
}
__device__ __forceinline__ float bf2f(unsigned short u) {
  unsigned int v = ((unsigned int)u) << 16;
  return __builtin_bit_cast(float, v);
}

__device__ __forceinline__ void async_ld16(const void* g, void* l) {
  __builtin_amdgcn_global_load_lds(
      (const __attribute__((address_space(1))) void*)g,
      (__attribute__((address_space(3))) void*)l, 16, 0, 0);
}

// ---------------- prep kernels ----------------
__global__ void cvt_x_kernel(const float* __restrict__ X, unsigned short* __restrict__ Y, int n4) {
  int i = blockIdx.x * 256 + threadIdx.x;
  if (i >= n4) return;
  const float4 xv = ((const float4*)X)[i];
  ushort4 o;
  o.x = f2bf(xv.x); o.y = f2bf(xv.y); o.z = f2bf(xv.z); o.w = f2bf(xv.w);
  ((ushort4*)Y)[i] = o;
}

// W[K][N] (row-major) -> Wt[N][K] bf16
__global__ void transp_w_kernel(const float* __restrict__ W, unsigned short* __restrict__ Wt,
                                int K, int N) {
  int idx = blockIdx.x * 256 + threadIdx.x;
  if (idx >= K * N) return;
  int n = idx / K, kk = idx % K;
  Wt[idx] = f2bf(W[kk * N + n]);
}

// ---------------- GEMM: C[M,N] = A[M,K] * Bt[N,K]^T (+bias, opt q-scale) ----------------
template <int N, int K, bool OUT_BF16, bool SCALE_Q>
__global__ __launch_bounds__(256)
void gemm_bt(const unsigned short* __restrict__ A,
             const unsigned short* __restrict__ Bt,
             void* __restrict__ Cv,
             const float* __restrict__ bias) {
  __shared__ __align__(16) unsigned short As[128 * 32];
  __shared__ __align__(16) unsigned short Bs[128 * 32];
  const int t    = threadIdx.x;
  const int wave = t >> 6;
  const int lane = t & 63;
  const int fr   = lane & 15;
  const int quad = lane >> 4;
  const int wr   = (wave >> 1) * 64;   // wave's row quadrant
  const int wc   = (wave & 1) * 64;    // wave's col quadrant
  const size_t m0 = (size_t)blockIdx.x * 128;
  const int    n0 = blockIdx.y * 128;

  f32x4 acc[4][4] = {};

  // staging: 512 chunks of 16B per tile; chunk = (wave*2+i)*64 + lane
  const int c0 = (wave * 2 + 0) * 64 + lane;
  const int c1 = (wave * 2 + 1) * 64 + lane;
  const unsigned short* ga0 = A + (m0 + (size_t)(c0 >> 2)) * K + (c0 & 3) * 8;
  const unsigned short* ga1 = A + (m0 + (size_t)(c1 >> 2)) * K + (c1 & 3) * 8;
  const unsigned short* gb0 = Bt + (size_t)(n0 + (c0 >> 2)) * K + (c0 & 3) * 8;
  const unsigned short* gb1 = Bt + (size_t)(n0 + (c1 >> 2)) * K + (c1 & 3) * 8;
  unsigned short* la0 = As + (wave * 2 + 0) * 64 * 8;
  unsigned short* la1 = As + (wave * 2 + 1) * 64 * 8;
  unsigned short* lb0 = Bs + (wave * 2 + 0) * 64 * 8;
  unsigned short* lb1 = Bs + (wave * 2 + 1) * 64 * 8;

  for (int kt = 0; kt < K; kt += 32) {
    async_ld16(ga0 + kt, la0);
    async_ld16(ga1 + kt, la1);
    async_ld16(gb0 + kt, lb0);
    async_ld16(gb1 + kt, lb1);
    __syncthreads();
    bf16x8 af[4], bfr[4];
#pragma unroll
    for (int r = 0; r < 4; ++r)
      af[r] = *(const bf16x8*)&As[(wr + r * 16 + fr) * 32 + quad * 8];
#pragma unroll
    for (int c = 0; c < 4; ++c)
      bfr[c] = *(const bf16x8*)&Bs[(wc + c * 16 + fr) * 32 + quad * 8];
#pragma unroll
    for (int r = 0; r < 4; ++r)
#pragma unroll
      for (int c = 0; c < 4; ++c)
        acc[r][c] = __builtin_amdgcn_mfma_f32_16x16x32_bf16(af[r], bfr[c], acc[r][c], 0, 0, 0);
    __syncthreads();
  }

  // epilogue: D layout col=lane&15, row=(lane>>4)*4+reg
#pragma unroll
  for (int r = 0; r < 4; ++r) {
#pragma unroll
    for (int i = 0; i < 4; ++i) {
      size_t m = m0 + wr + r * 16 + quad * 4 + i;
#pragma unroll
      for (int c = 0; c < 4; ++c) {
        int n = n0 + wc + c * 16 + fr;
        float v = acc[r][c][i] + bias[n];
        if (SCALE_Q && n < DIM) v *= QSCALE;
        if (OUT_BF16)
          ((unsigned short*)Cv)[m * N + n] = f2bf(v);
        else
          ((float*)Cv)[m * N + n] = v;
      }
    }
  }
}

// ---------------- attention: one block per (window, head) ----------------
__global__ __launch_bounds__(256)
void attn_kernel(const unsigned short* __restrict__ qkv,
                 const float* __restrict__ bias_table,
                 const int* __restrict__ rel_idx,
                 unsigned short* __restrict__ ao) {
  const int b = blockIdx.x, h = blockIdx.y, t = threadIdx.x;
  __shared__ float q[52][32], k[52][32], v[52][32];
  __shared__ float S[52][52];
  const unsigned short* base = qkv + (size_t)b * NTOK * QKVN + h * 32;
  for (int e = t; e < 52 * 32; e += 256) {
    int i = e >> 5, d = e & 31;
    if (i < NTOK) {
      q[i][d] = bf2f(base[i * QKVN + d]);
      k[i][d] = bf2f(base[i * QKVN + DIM + d]);
      v[i][d] = bf2f(base[i * QKVN + 2 * DIM + d]);
    } else {
      q[i][d] = 0.f; k[i][d] = 0.f; v[i][d] = 0.f;
    }
  }
  __syncthreads();

  // S = q k^T + bias, 4x4 register tiles; 13x13=169 tiles
  if (t < 169) {
    const int ib = (t % 13) * 4, jb = (t / 13) * 4;
    float accS[4][4] = {};
#pragma unroll
    for (int d = 0; d < 32; d += 4) {
      float4 qr[4], kr[4];
#pragma unroll
      for (int a = 0; a < 4; ++a) qr[a] = *(const float4*)&q[ib + a][d];
#pragma unroll
      for (int a = 0; a < 4; ++a) kr[a] = *(const float4*)&k[jb + a][d];
#pragma unroll
      for (int a = 0; a < 4; ++a)
#pragma unroll
        for (int c = 0; c < 4; ++c)
          accS[a][c] += qr[a].x * kr[c].x + qr[a].y * kr[c].y +
                        qr[a].z * kr[c].z + qr[a].w * kr[c].w;
    }
#pragma unroll
    for (int a = 0; a < 4; ++a) {
      int i = ib + a;
      if (i < NTOK) {
#pragma unroll
        for (int c = 0; c < 4; ++c) {
          int j = jb + c;
          if (j < NTOK)
            S[i][j] = accS[a][c] + bias_table[rel_idx[i * NTOK + j] * NHEADS + h];
        }
      }
    }
  }
  __syncthreads();

  // row softmax
  if (t < NTOK) {
    float mx = -1e30f;
    for (int j = 0; j < NTOK; ++j) mx = fmaxf(mx, S[t][j]);
    float sum = 0.f;
    for (int j = 0; j < NTOK; ++j) { float e = __expf(S[t][j] - mx); S[t][j] = e; sum += e; }
    float inv = 1.f / sum;
    for (int j = 0; j < NTOK; ++j) S[t][j] *= inv;
  } else if (t < 52) {
    for (int j = 0; j < 52; ++j) S[t][j] = 0.f;  // pad rows -> harmless zeros
  }
  __syncthreads();

  // O = P v, 4(i) x 4(d) register tiles; 13x8=104 tiles
  if (t < 104) {
    const int ib = (t % 13) * 4, db = (t / 13) * 4;
    float accO[4][4] = {};
    for (int j = 0; j < NTOK; ++j) {
      const float4 vr = *(const float4*)&v[j][db];
      const float p0 = S[ib][j], p1 = S[ib + 1][j], p2 = S[ib + 2][j], p3 = S[ib + 3][j];
      accO[0][0] += p0 * vr.x; accO[0][1] += p0 * vr.y; accO[0][2] += p0 * vr.z; accO[0][3] += p0 * vr.w;
      accO[1][0] += p1 * vr.x; accO[1][1] += p1 * vr.y; accO[1][2] += p1 * vr.z; accO[1][3] += p1 * vr.w;
      accO[2][0] += p2 * vr.x; accO[2][1] += p2 * vr.y; accO[2][2] += p2 * vr.z; accO[2][3] += p2 * vr.w;
      accO[3][0] += p3 * vr.x; accO[3][1] += p3 * vr.y; accO[3][2] += p3 * vr.z; accO[3][3] += p3 * vr.w;
    }
    unsigned short* obase = ao + (size_t)b * NTOK * DIM + h * 32 + db;
#pragma unroll
    for (int a = 0; a < 4; ++a) {
      int i = ib + a;
      if (i < NTOK) {
#pragma unroll
        for (int c = 0; c < 4; ++c)
          obase[(size_t)i * DIM + c] = f2bf(accO[a][c]);
      }
    }
  }
}

// ---------------- launch ----------------
extern "C" void kernel_launch(void* const* d_in, const int* in_sizes, int n_in,
                              void* d_out, int out_size, void* d_ws, size_t ws_size,
                              hipStream_t stream) {
  const float* x          = (const float*)d_in[0];
  const float* qkv_w      = (const float*)d_in[1];
  const float* qkv_b      = (const float*)d_in[2];
  const float* proj_w     = (const float*)d_in[3];
  const float* proj_b     = (const float*)d_in[4];
  const float* bias_table = (const float*)d_in[5];
  const int*   rel_idx    = (const int*)d_in[6];

  char* ws = (char*)d_ws;
  const size_t SZ_XBF  = (size_t)MTOT * DIM * 2;   // 154,140,672
  const size_t SZ_W1T  = (size_t)QKVN * DIM * 2;   // 884,736
  const size_t SZ_W2T  = (size_t)DIM * DIM * 2;    // 294,912
  const size_t SZ_QKV  = (size_t)MTOT * QKVN * 2;  // 462,422,016
  unsigned short* x_bf = (unsigned short*)(ws);
  unsigned short* w1t  = (unsigned short*)(ws + SZ_XBF);
  unsigned short* w2t  = (unsigned short*)(ws + SZ_XBF + SZ_W1T);
  unsigned short* qkv  = (unsigned short*)(ws + SZ_XBF + SZ_W1T + SZ_W2T);
  unsigned short* ao   = (unsigned short*)(ws + SZ_XBF + SZ_W1T + SZ_W2T + SZ_QKV);

  const int n4 = MTOT * DIM / 4;  // 19,267,584
  hipLaunchKernelGGL(cvt_x_kernel, dim3((n4 + 255) / 256), dim3(256), 0, stream, x, x_bf, n4);
  hipLaunchKernelGGL(transp_w_kernel, dim3((DIM * QKVN + 255) / 256), dim3(256), 0, stream,
                     qkv_w, w1t, DIM, QKVN);
  hipLaunchKernelGGL(transp_w_kernel, dim3((DIM * DIM + 255) / 256), dim3(256), 0, stream,
                     proj_w, w2t, DIM, DIM);
  hipLaunchKernelGGL((gemm_bt<QKVN, DIM, true, true>), dim3(MTOT / 128, QKVN / 128), dim3(256),
                     0, stream, x_bf, w1t, (void*)qkv, qkv_b);
  hipLaunchKernelGGL(attn_kernel, dim3(NWIN, NHEADS), dim3(256), 0, stream,
                     qkv, bias_table, rel_idx, ao);
  hipLaunchKernelGGL((gemm_bt<DIM, DIM, false, false>), dim3(MTOT / 128, DIM / 128), dim3(256),
                     0, stream, ao, w2t, d_out, proj_b);
}